// Round 13
// baseline (1242.832 us; speedup 1.0000x reference)
//
#include <hip/hip_runtime.h>
#include <cstddef>

#define NN 50000
#define NE 800000
#define NG 128
#define IND 100
#define HID 256
#define NSTEPS 5
#define PCH 8

typedef __attribute__((ext_vector_type(8))) short bf16x8;   // 8 bf16 = 4 VGPRs
typedef __attribute__((ext_vector_type(4))) float f32x4;

__device__ __forceinline__ float b2f(unsigned h) { return __uint_as_float(h << 16); }
__device__ __forceinline__ unsigned short f2b(float f) {
    unsigned u = __float_as_uint(f);
    unsigned r = (u + 0x7FFFu + ((u >> 16) & 1u)) >> 16;   // RNE
    return (unsigned short)r;
}
__device__ __forceinline__ float sigm(float x) { return 1.f / (1.f + __expf(-x)); }
__device__ __forceinline__ float tanh_fast(float x) { return 1.f - 2.f / (1.f + __expf(2.f * x)); }

// =====================================================================
// bf16 MFMA GEMM: C[M,N](bf16) = act(A[M,K]bf16 @ Bt[N,K]bf16^T + bias)
// BM=BN=128, BK=32. 256 thr = 4 waves (2x2), wave tile 64x64.
// blockIdx.z batching: Bt += z*btz, C += z*cz. If Cf != nullptr, also
// writes the fp32 result to Cf (C gets the bf16 mirror).
// =====================================================================
#define LSTR 40
__global__ __launch_bounds__(256) void gemm_bf16(const unsigned short* __restrict__ A,
                                                 const unsigned short* __restrict__ Bt,
                                                 const float* __restrict__ bias, int act,
                                                 unsigned short* __restrict__ C,
                                                 float* __restrict__ Cf,
                                                 int M, int N, int K,
                                                 size_t btz, size_t cz)
{
    Bt += (size_t)blockIdx.z * btz;
    C  += (size_t)blockIdx.z * cz;
    __shared__ unsigned short As[128 * LSTR];
    __shared__ unsigned short Bs[128 * LSTR];
    const int tid  = threadIdx.x;
    const int row0 = blockIdx.y * 128;
    const int col0 = blockIdx.x * 128;
    const int wave = tid >> 6, lane = tid & 63;
    const int wm = wave >> 1, wn = wave & 1;
    const int lr = lane & 15, q = lane >> 4;
    const int r_st = tid >> 2;
    const int ks   = tid & 3;

    f32x4 acc[4][4];
    #pragma unroll
    for (int i = 0; i < 4; ++i)
        #pragma unroll
        for (int j = 0; j < 4; ++j) acc[i][j] = (f32x4){0.f, 0.f, 0.f, 0.f};

    for (int k0 = 0; k0 < K; k0 += 32) {
        #pragma unroll
        for (int it = 0; it < 2; ++it) {
            int r  = r_st + it * 64;
            int ga = min(row0 + r, M - 1);
            uint4 av = *(const uint4*)(A + (size_t)ga * K + k0 + ks * 8);
            *(uint4*)(As + r * LSTR + ks * 8) = av;
            uint4 bv = *(const uint4*)(Bt + (size_t)(col0 + r) * K + k0 + ks * 8);
            *(uint4*)(Bs + r * LSTR + ks * 8) = bv;
        }
        __syncthreads();
        bf16x8 af[4], bfr[4];
        #pragma unroll
        for (int i = 0; i < 4; ++i)
            af[i]  = *(const bf16x8*)(As + (wm * 64 + i * 16 + lr) * LSTR + q * 8);
        #pragma unroll
        for (int j = 0; j < 4; ++j)
            bfr[j] = *(const bf16x8*)(Bs + (wn * 64 + j * 16 + lr) * LSTR + q * 8);
        #pragma unroll
        for (int i = 0; i < 4; ++i)
            #pragma unroll
            for (int j = 0; j < 4; ++j)
                acc[i][j] = __builtin_amdgcn_mfma_f32_16x16x32_bf16(af[i], bfr[j], acc[i][j], 0, 0, 0);
        __syncthreads();
    }
    #pragma unroll
    for (int i = 0; i < 4; ++i) {
        int rbase = row0 + wm * 64 + i * 16 + q * 4;
        #pragma unroll
        for (int j = 0; j < 4; ++j) {
            int col = col0 + wn * 64 + j * 16 + lr;
            if (col >= N) continue;
            float badd = bias ? bias[col] : 0.f;
            #pragma unroll
            for (int r = 0; r < 4; ++r) {
                int row = rbase + r;
                if (row < M) {
                    float v = acc[i][j][r] + badd;
                    if (act) v = fmaxf(v, 0.f);
                    C[(size_t)row * N + col] = f2b(v);
                    if (Cf) Cf[(size_t)row * N + col] = v;
                }
            }
        }
    }
}

// =====================================================================
// Fused GRU v9 (empirical optimum of 7 structural variants):
// acc merged to 4 sets (r, z share gi+gh accumulators) = 64 AGPRs;
// 64 arch VGPRs -> 128 total = exactly 512/4 -> 4 waves/EU, no spill.
// 64 rows x 64 cols, 4 waves side-by-side. A staged per-32k via LDS w/
// 1-deep prefetch (deeper prefetch spills: R7/R10); weights direct
// global->VGPR (L2-resident). h fp32 in place + bf16 mirror.
// =====================================================================
__global__ __launch_bounds__(256, 4) void gru_mfma(const unsigned short* __restrict__ agg,
                                                   const unsigned short* __restrict__ hbf,
                                                   float* __restrict__ h,
                                                   unsigned short* __restrict__ hbfo,
                                                   const unsigned short* __restrict__ Wgi,
                                                   const unsigned short* __restrict__ Wgh,
                                                   const float* __restrict__ bih,
                                                   const float* __restrict__ bhh,
                                                   int M, int dorelu)
{
    __shared__ unsigned short Sa[64 * LSTR];
    __shared__ unsigned short Sh[64 * LSTR];
    const int tid  = threadIdx.x;
    const int row0 = blockIdx.y * 64;
    const int col0 = blockIdx.x * 64;
    const int wave = tid >> 6, lane = tid & 63;
    const int lr = lane & 15, q = lane >> 4;
    const int cw = col0 + wave * 16;       // this wave's 16 output cols
    const int r_st = tid >> 2, ks = tid & 3;

    // acc sets: 0 = r (agg+hbf), 1 = z (agg+hbf), 2 = i_n (agg), 3 = h_n (hbf)
    f32x4 acc[4][4];
    #pragma unroll
    for (int g = 0; g < 4; ++g)
        #pragma unroll
        for (int i = 0; i < 4; ++i) acc[g][i] = (f32x4){0.f, 0.f, 0.f, 0.f};

    const int ga = min(row0 + r_st, M - 1);
    uint4 pa = *(const uint4*)(agg + (size_t)ga * HID + ks * 8);
    uint4 ph = *(const uint4*)(hbf + (size_t)ga * HID + ks * 8);

    #pragma unroll
    for (int kk = 0; kk < 8; ++kk) {
        const int k0 = kk * 32;
        __syncthreads();
        *(uint4*)(Sa + r_st * LSTR + ks * 8) = pa;
        *(uint4*)(Sh + r_st * LSTR + ks * 8) = ph;
        __syncthreads();
        if (kk < 7) {
            pa = *(const uint4*)(agg + (size_t)ga * HID + k0 + 32 + ks * 8);
            ph = *(const uint4*)(hbf + (size_t)ga * HID + k0 + 32 + ks * 8);
        }
        // 6 weight fragments straight from global (L2-resident)
        bf16x8 wir = *(const bf16x8*)(Wgi + (size_t)(0*HID + cw + lr) * HID + k0 + q * 8);
        bf16x8 wiz = *(const bf16x8*)(Wgi + (size_t)(1*HID + cw + lr) * HID + k0 + q * 8);
        bf16x8 win = *(const bf16x8*)(Wgi + (size_t)(2*HID + cw + lr) * HID + k0 + q * 8);
        bf16x8 whr = *(const bf16x8*)(Wgh + (size_t)(0*HID + cw + lr) * HID + k0 + q * 8);
        bf16x8 whz = *(const bf16x8*)(Wgh + (size_t)(1*HID + cw + lr) * HID + k0 + q * 8);
        bf16x8 whn = *(const bf16x8*)(Wgh + (size_t)(2*HID + cw + lr) * HID + k0 + q * 8);
        bf16x8 afa[4], afh[4];
        #pragma unroll
        for (int i = 0; i < 4; ++i) {
            afa[i] = *(const bf16x8*)(Sa + (i * 16 + lr) * LSTR + q * 8);
            afh[i] = *(const bf16x8*)(Sh + (i * 16 + lr) * LSTR + q * 8);
        }
        #pragma unroll
        for (int i = 0; i < 4; ++i) {
            acc[0][i] = __builtin_amdgcn_mfma_f32_16x16x32_bf16(afa[i], wir, acc[0][i], 0, 0, 0);
            acc[0][i] = __builtin_amdgcn_mfma_f32_16x16x32_bf16(afh[i], whr, acc[0][i], 0, 0, 0);
            acc[1][i] = __builtin_amdgcn_mfma_f32_16x16x32_bf16(afa[i], wiz, acc[1][i], 0, 0, 0);
            acc[1][i] = __builtin_amdgcn_mfma_f32_16x16x32_bf16(afh[i], whz, acc[1][i], 0, 0, 0);
            acc[2][i] = __builtin_amdgcn_mfma_f32_16x16x32_bf16(afa[i], win, acc[2][i], 0, 0, 0);
            acc[3][i] = __builtin_amdgcn_mfma_f32_16x16x32_bf16(afh[i], whn, acc[3][i], 0, 0, 0);
        }
    }

    // epilogue: col cg fixed per lane; biases loaded once
    const int cg = cw + lr;
    const float brr = bih[cg]         + bhh[cg];
    const float bzz = bih[HID + cg]   + bhh[HID + cg];
    const float bin = bih[2*HID + cg];
    const float bhn = bhh[2*HID + cg];
    #pragma unroll
    for (int i = 0; i < 4; ++i) {
        #pragma unroll
        for (int r = 0; r < 4; ++r) {
            int row = row0 + i * 16 + q * 4 + r;
            if (row < M) {
                float rr = sigm(acc[0][i][r] + brr);
                float zz = sigm(acc[1][i][r] + bzz);
                float nn = tanh_fast(acc[2][i][r] + bin + rr * (acc[3][i][r] + bhn));
                size_t off = (size_t)row * HID + cg;
                float hv = h[off];
                float o = (1.f - zz) * nn + zz * hv;
                if (dorelu) o = fmaxf(o, 0.f);
                h[off] = o;
                hbfo[off] = f2b(o);
            }
        }
    }
}

// ---------- fp32 tiled GEMM (classifier only) ----------
template<int ACT>
__global__ __launch_bounds__(256) void gemm_kn(const float* __restrict__ A,
                                               const float* __restrict__ B,
                                               const float* __restrict__ bias,
                                               float* __restrict__ C,
                                               int M, int N, int K)
{
    __shared__ float As[64][17];
    __shared__ float Bs[16][65];
    const int tid  = threadIdx.x;
    const int row0 = blockIdx.y * 64;
    const int col0 = blockIdx.x * 64;
    const int tr = tid >> 4, tc = tid & 15;
    const int ar = tid >> 2, akq = tid & 3;
    const int bk = tid >> 4, bj = (tid & 15) << 2;

    float acc[4][4] = {};
    for (int k0 = 0; k0 < K; k0 += 16) {
        float4 av = make_float4(0.f,0.f,0.f,0.f);
        if (row0 + ar < M && (k0 + (akq<<2)) < K)
            av = *(const float4*)(A + (size_t)(row0+ar)*K + k0 + (akq<<2));
        As[ar][(akq<<2)+0] = av.x; As[ar][(akq<<2)+1] = av.y;
        As[ar][(akq<<2)+2] = av.z; As[ar][(akq<<2)+3] = av.w;
        float4 bv = make_float4(0.f,0.f,0.f,0.f);
        if (k0 + bk < K)
            bv = *(const float4*)(B + (size_t)(k0+bk)*N + col0 + bj);
        Bs[bk][bj+0] = bv.x; Bs[bk][bj+1] = bv.y; Bs[bk][bj+2] = bv.z; Bs[bk][bj+3] = bv.w;
        __syncthreads();
        #pragma unroll
        for (int k = 0; k < 16; ++k) {
            float a4[4], b4[4];
            #pragma unroll
            for (int i = 0; i < 4; ++i) a4[i] = As[(tr<<2)+i][k];
            #pragma unroll
            for (int j = 0; j < 4; ++j) b4[j] = Bs[k][(tc<<2)+j];
            #pragma unroll
            for (int i = 0; i < 4; ++i)
                #pragma unroll
                for (int j = 0; j < 4; ++j) acc[i][j] += a4[i]*b4[j];
        }
        __syncthreads();
    }
    #pragma unroll
    for (int i = 0; i < 4; ++i) {
        int row = row0 + (tr<<2) + i;
        if (row >= M) continue;
        #pragma unroll
        for (int j = 0; j < 4; ++j) {
            int col = col0 + (tc<<2) + j;
            float v = acc[i][j];
            if (bias) v += bias[col];
            if (ACT == 1) v = fmaxf(v, 0.f);
            C[(size_t)row*N + col] = v;
        }
    }
}

// ---------- CSR build ----------
__global__ void edge_count(const int* __restrict__ dst, int* __restrict__ cnt, int E) {
    int e = blockIdx.x*256 + threadIdx.x;
    if (e < E) atomicAdd(&cnt[dst[e]], 1);
}
__global__ void scan_bsums(const int* __restrict__ cnt, int* __restrict__ bsum, int n) {
    __shared__ int sd[512];
    int tid = threadIdx.x, i = blockIdx.x*512 + tid;
    sd[tid] = (i < n) ? cnt[i] : 0;
    __syncthreads();
    for (int off = 256; off > 0; off >>= 1) {
        if (tid < off) sd[tid] += sd[tid+off];
        __syncthreads();
    }
    if (tid == 0) bsum[blockIdx.x] = sd[0];
}
__global__ void scan_top(int* __restrict__ bsum, int nb) {   // single block, 128 thr
    __shared__ int sd[128];
    int tid = threadIdx.x;
    int v = (tid < nb) ? bsum[tid] : 0;
    sd[tid] = v;
    __syncthreads();
    for (int off = 1; off < 128; off <<= 1) {
        int t = (tid >= off) ? sd[tid-off] : 0;
        __syncthreads();
        sd[tid] += t;
        __syncthreads();
    }
    if (tid < nb) bsum[tid] = sd[tid] - v;   // exclusive
}
__global__ void scan_local(const int* __restrict__ cnt, const int* __restrict__ bsum,
                           int* __restrict__ rp, int n) {
    __shared__ int sd[512];
    int tid = threadIdx.x, i = blockIdx.x*512 + tid;
    int v = (i < n) ? cnt[i] : 0;
    sd[tid] = v;
    __syncthreads();
    for (int off = 1; off < 512; off <<= 1) {
        int t = (tid >= off) ? sd[tid-off] : 0;
        __syncthreads();
        sd[tid] += t;
        __syncthreads();
    }
    if (i < n) rp[i] = bsum[blockIdx.x] + sd[tid] - v;
    if (i == n-1) rp[n] = bsum[blockIdx.x] + sd[tid];
}
__global__ void edge_fill(const int* __restrict__ src, const int* __restrict__ dst,
                          const int* __restrict__ rp, int* __restrict__ cur,
                          int* __restrict__ ci, int E) {
    int e = blockIdx.x*256 + threadIdx.x;
    if (e < E) {
        int d = dst[e];
        int pos = rp[d] + atomicAdd(&cur[d], 1);
        ci[pos] = src[e];
    }
}

// =====================================================================
// gather v3: one wave per node; 32 lanes cover one 512B row (16B/lane),
// wave halves take even/odd neighbors. Single uniform loop processes 16
// neighbors/iter with 8 loads in flight PER LANE; the final partial batch
// is predicated (load-or-zero), so low-degree nodes also get 8-deep MLP
// instead of a serial 2-at-a-time tail (the v2 latency chain).
// =====================================================================
__global__ void gather_agg(const unsigned short* __restrict__ m, unsigned short* __restrict__ agg,
                           const int* __restrict__ rp, const int* __restrict__ ci, int M)
{
    int node = blockIdx.x*4 + (threadIdx.x >> 6);
    int lane = threadIdx.x & 63;
    if (node >= M) return;
    const int half = lane >> 5;      // 0: even neighbors, 1: odd
    const int li   = lane & 31;      // 16B slice (8 bf16) within the row
    const int s = rp[node], e = rp[node+1];
    float a[8] = {0.f,0.f,0.f,0.f,0.f,0.f,0.f,0.f};
    for (int p = s; p < e; p += 16) {
        uint4 v[8];
        #pragma unroll
        for (int u = 0; u < 8; ++u) {
            int idx = p + 2*u + half;
            if (idx < e) {
                int r = ci[idx];
                v[u] = *(const uint4*)(m + (size_t)r * HID + li * 8);
            } else {
                v[u] = make_uint4(0u, 0u, 0u, 0u);   // b2f(0) == 0.0f
            }
        }
        #pragma unroll
        for (int u = 0; u < 8; ++u) {
            a[0] += b2f(v[u].x & 0xffffu); a[1] += b2f(v[u].x >> 16);
            a[2] += b2f(v[u].y & 0xffffu); a[3] += b2f(v[u].y >> 16);
            a[4] += b2f(v[u].z & 0xffffu); a[5] += b2f(v[u].z >> 16);
            a[6] += b2f(v[u].w & 0xffffu); a[7] += b2f(v[u].w >> 16);
        }
    }
    #pragma unroll
    for (int u = 0; u < 8; ++u) a[u] += __shfl_xor(a[u], 32, 64);
    if (half == 0) {
        uint4 o;
        o.x = (unsigned)f2b(a[0]) | ((unsigned)f2b(a[1]) << 16);
        o.y = (unsigned)f2b(a[2]) | ((unsigned)f2b(a[3]) << 16);
        o.z = (unsigned)f2b(a[4]) | ((unsigned)f2b(a[5]) << 16);
        o.w = (unsigned)f2b(a[6]) | ((unsigned)f2b(a[7]) << 16);
        *(uint4*)(agg + (size_t)node * HID + li * 8) = o;
    }
}

// ---------- input split-precision prep ----------
// A' row n: cols [0,128) = bf16(x) (hi), cols [128,256) = bf16(x - hi); pad k>=100 with 0
__global__ void split_x(const float* __restrict__ x, unsigned short* __restrict__ A) {
    int n = blockIdx.x, k = threadIdx.x;   // 128 threads
    unsigned short hi = 0, lo = 0;
    if (k < IND) {
        float v = x[(size_t)n * IND + k];
        hi = f2b(v);
        lo = f2b(v - b2f(hi));
    }
    A[(size_t)n * 256 + k]       = hi;
    A[(size_t)n * 256 + 128 + k] = lo;
}
// Bt' row n (output col): cols [0,128) = bf16(W_in[k][n]), cols [128,256) same; pad 0
__global__ void prep_win(const float* __restrict__ w, unsigned short* __restrict__ bt) {
    int n = blockIdx.x, k = threadIdx.x;   // 256 blocks x 128 threads
    unsigned short v = (k < IND) ? f2b(w[(size_t)k * HID + n]) : (unsigned short)0;
    bt[(size_t)n * 256 + k]       = v;
    bt[(size_t)n * 256 + 128 + k] = v;
}

__global__ void cvt_elem(const float* __restrict__ src, unsigned short* __restrict__ dst, int n) {
    int i = blockIdx.x*256 + threadIdx.x;
    if (i < n) dst[i] = f2b(src[i]);
}
// Wa1 [256][128] ([k][n]) -> Wa1t bf16 [128][256] ([n][k])
__global__ void prep_wa1(const float* __restrict__ w, unsigned short* __restrict__ wt) {
    int n = blockIdx.x, k = threadIdx.x;
    wt[(size_t)n*HID + k] = f2b(w[(size_t)k*128 + n]);
}

// ---------- attention scalar head ----------
__global__ void att_sig(const unsigned short* __restrict__ t, const float* __restrict__ Wa2,
                        const float* __restrict__ ba2, float* __restrict__ a, int M)
{
    int node = blockIdx.x*4 + (threadIdx.x >> 6);
    int lane = threadIdx.x & 63;
    if (node >= M) return;
    float s = b2f(t[(size_t)node*128 + lane])*Wa2[lane]
            + b2f(t[(size_t)node*128 + 64 + lane])*Wa2[64+lane];
    #pragma unroll
    for (int off = 32; off > 0; off >>= 1) s += __shfl_down(s, off, 64);
    if (lane == 0) a[node] = 1.f/(1.f+__expf(-(s + ba2[0])));
}

// ---------- pooling, two-phase (reads bf16 h mirror — halves read traffic) ----------
__device__ __forceinline__ int lowerb(const int* arr, int n, int val) {
    int lo = 0, hi = n;
    while (lo < hi) { int mid = (lo+hi)>>1; if (arr[mid] < val) lo = mid+1; else hi = mid; }
    return lo;
}
__global__ void pool_partial(const unsigned short* __restrict__ hbf, const float* __restrict__ a,
                             const int* __restrict__ batch, float* __restrict__ part, int M)
{
    int g = blockIdx.x, c = blockIdx.y, j = threadIdx.x;
    int lo = lowerb(batch, M, g);
    int hi = lowerb(batch, M, g+1);
    int len = hi - lo, per = (len + PCH - 1) / PCH;
    int s = lo + c * per, e = min(s + per, hi);
    float sum = 0.f, mx = 0.f;
    for (int n = s; n < e; ++n) {
        float v = b2f(hbf[(size_t)n*HID + j]) * a[n];
        sum += v; mx = fmaxf(mx, v);
    }
    float* pp = part + ((size_t)g*PCH + c) * 512;
    pp[j] = sum; pp[256 + j] = mx;
}
__global__ void pool_final(const float* __restrict__ part, const int* __restrict__ batch,
                           float* __restrict__ gout, int M)
{
    int g = blockIdx.x, j = threadIdx.x;
    float sum = 0.f, mx = 0.f;
    for (int c = 0; c < PCH; ++c) {
        const float* pp = part + ((size_t)g*PCH + c) * 512;
        sum += pp[j];
        mx = fmaxf(mx, pp[256 + j]);
    }
    int lo = lowerb(batch, M, g);
    int hi = lowerb(batch, M, g+1);
    float cnt = (float)(hi - lo);
    gout[(size_t)g*512 + j]       = sum / fmaxf(cnt, 1.f);
    gout[(size_t)g*512 + 256 + j] = mx;   // wx >= 0 so 0-init == where(count>0,max,0)
}

__global__ void preds_kernel(const float* __restrict__ g2, const float* __restrict__ W,
                             const float* __restrict__ b, float* __restrict__ out)
{
    int t = threadIdx.x;
    int row = t >> 1, col = t & 1;
    float s = b[col];
    for (int k = 0; k < 128; ++k) s += g2[row*128 + k] * W[k*2 + col];
    out[row*2 + col] = s;
}

extern "C" void kernel_launch(void* const* d_in, const int* in_sizes, int n_in,
                              void* d_out, int out_size, void* d_ws, size_t ws_size,
                              hipStream_t stream)
{
    const float* x     = (const float*)d_in[0];
    const int*   eidx  = (const int*)  d_in[1];
    const int*   batch = (const int*)  d_in[2];
    const float* W_in  = (const float*)d_in[3];
    const float* b_in  = (const float*)d_in[4];
    const float* ggc_w = (const float*)d_in[5];
    const float* W_ih  = (const float*)d_in[6];
    const float* W_hh  = (const float*)d_in[7];
    const float* b_ih  = (const float*)d_in[8];
    const float* b_hh  = (const float*)d_in[9];
    const float* Wa1   = (const float*)d_in[10];
    const float* ba1   = (const float*)d_in[11];
    const float* Wa2   = (const float*)d_in[12];
    const float* ba2   = (const float*)d_in[13];
    const float* Wc1   = (const float*)d_in[14];
    const float* bc1   = (const float*)d_in[15];
    const float* Wc2   = (const float*)d_in[16];
    const float* bc2   = (const float*)d_in[17];
    const float* Wc3   = (const float*)d_in[18];
    const float* bc3   = (const float*)d_in[19];

    float* out  = (float*)d_out;
    float* aout = out + NG*2;

    // ---- workspace layout (~138 MB; known-safe budget 158 MB) ----
    char* p = (char*)d_ws;
    auto alloc = [&](size_t bytes) -> char* {
        char* r = p; p += (bytes + 255) & ~(size_t)255; return r;
    };
    float*          hf    = (float*)alloc((size_t)NN*HID*4);           // 51.2 MB
    unsigned short* hbfP  = (unsigned short*)alloc((size_t)NN*HID*2);  // 25.6 MB
    unsigned short* hbfQ  = (unsigned short*)alloc((size_t)NN*HID*2);  // 25.6 MB (aliased as split-x A')
    unsigned short* aggbf = (unsigned short*)alloc((size_t)NN*HID*2);  // 25.6 MB (reused as tbuf)
    int* row_ptr = (int*)alloc((NN+1)*4);
    int* cursor  = (int*)alloc(NN*4);
    int* col_idx = (int*)alloc((size_t)NE*4);
    int* bsum    = (int*)alloc(128*4);
    unsigned short* wgbf   = (unsigned short*)alloc((size_t)NSTEPS*HID*HID*2);  // ggc_w bf16 [s][k][j]
    unsigned short* WihBf  = (unsigned short*)alloc((size_t)768*HID*2);         // [768][256]
    unsigned short* WhhBf  = (unsigned short*)alloc((size_t)768*HID*2);
    unsigned short* WcombT = (unsigned short*)alloc((size_t)NSTEPS*768*HID*2);  // 2.0 MB
    unsigned short* Wa1t   = (unsigned short*)alloc((size_t)128*HID*2);
    unsigned short* WinT   = (unsigned short*)alloc((size_t)256*256*2);         // 131 KB
    float* part = (float*)alloc((size_t)NG*PCH*512*4);                          // 2.0 MB
    float* gbuf = (float*)alloc((size_t)NG*2*HID*4);
    float* g1   = (float*)alloc((size_t)NG*HID*4);
    float* g2   = (float*)alloc((size_t)NG*128*4);

    const int* esrc = eidx;
    const int* edst = eidx + NE;
    dim3 blk(256);
    const int NB512 = (NN + 511) / 512;   // 98

    // CSR build
    hipMemsetAsync(cursor, 0, NN*sizeof(int), stream);
    edge_count<<<NE/256, blk, 0, stream>>>(edst, cursor, NE);
    scan_bsums<<<NB512, 512, 0, stream>>>(cursor, bsum, NN);
    scan_top<<<1, 128, 0, stream>>>(bsum, NB512);
    scan_local<<<NB512, 512, 0, stream>>>(cursor, bsum, row_ptr, NN);
    hipMemsetAsync(cursor, 0, NN*sizeof(int), stream);
    edge_fill<<<NE/256, blk, 0, stream>>>(esrc, edst, row_ptr, cursor, col_idx, NE);

    // weight prep (bf16) + combined gi weights: WcombT_s = Wih @ w_s^T  [768x256], batched over s
    cvt_elem<<<(NSTEPS*HID*HID + 255)/256, blk, 0, stream>>>(ggc_w, wgbf, NSTEPS*HID*HID);
    cvt_elem<<<768, blk, 0, stream>>>(W_ih, WihBf, 768*HID);
    cvt_elem<<<768, blk, 0, stream>>>(W_hh, WhhBf, 768*HID);
    prep_wa1<<<128, blk, 0, stream>>>(Wa1, Wa1t);
    gemm_bf16<<<dim3(2, 6, NSTEPS), blk, 0, stream>>>(
        WihBf, wgbf, nullptr, 0, WcombT, nullptr, 768, HID, HID,
        (size_t)HID*HID, (size_t)768*HID);

    // input projection via split-precision bf16 MFMA:
    //   A' = [bf16(x) | bf16(x - hi)]  (K=256, zero-padded from 100)
    //   B' = [W_hi | W_hi]  ->  h0 = x @ W_hi exactly in x, W rounded once.
    // Writes fp32 hf + bf16 hbfP in one pass. A' aliases hbfQ (dead until gru s0).
    unsigned short* Ax = hbfQ;
    split_x<<<NN, 128, 0, stream>>>(x, Ax);
    prep_win<<<256, 128, 0, stream>>>(W_in, WinT);
    gemm_bf16<<<dim3(2, (NN+127)/128), blk, 0, stream>>>(
        Ax, WinT, b_in, 1, hbfP, hf, NN, HID, 256, 0, 0);

    // 5 steps: gather h -> agg_h; gru with combined gi weights (no m-GEMM).
    // Last step fuses the post-loop relu into the gru epilogue.
    unsigned short* hbf  = hbfP;
    unsigned short* hbfn = hbfQ;
    const int MB64 = (NN + 63) / 64;   // 782
    for (int s = 0; s < NSTEPS; ++s) {
        gather_agg<<<NN/4, blk, 0, stream>>>(hbf, aggbf, row_ptr, col_idx, NN);
        gru_mfma<<<dim3(HID/64, MB64), blk, 0, stream>>>(
            aggbf, hbf, hf, hbfn, WcombT + (size_t)s*768*HID, WhhBf, b_ih, b_hh,
            NN, (s == NSTEPS-1) ? 1 : 0);
        unsigned short* t0 = hbf; hbf = hbfn; hbfn = t0;
    }
    // hf now holds relu(h5); hbf holds its bf16 mirror.

    // attention: t = relu(h @ Wa1 + ba1) [bf16, reuses aggbf], a = sigmoid(t @ Wa2 + ba2)
    unsigned short* tbuf = aggbf;
    gemm_bf16<<<dim3(1, (NN+127)/128), blk, 0, stream>>>(hbf, Wa1t, ba1, 1, tbuf, nullptr, NN, 128, HID, 0, 0);
    att_sig<<<NN/4, blk, 0, stream>>>(tbuf, Wa2, ba2, aout, NN);

    // pooling -> g [128, 512] (two-phase, bf16 h mirror)
    pool_partial<<<dim3(NG, PCH), blk, 0, stream>>>(hbf, aout, batch, part, NN);
    pool_final<<<NG, blk, 0, stream>>>(part, batch, gbuf, NN);

    // classifier (fp32, tiny)
    gemm_kn<1><<<dim3(HID/64, (NG+63)/64), blk, 0, stream>>>(gbuf, Wc1, bc1, g1, NG, HID, 2*HID);
    gemm_kn<1><<<dim3(2,      (NG+63)/64), blk, 0, stream>>>(g1,   Wc2, bc2, g2, NG, 128, HID);
    preds_kernel<<<1, blk, 0, stream>>>(g2, Wc3, bc3, out);
}

// Round 14
// 1234.843 us; speedup vs baseline: 1.0065x; 1.0065x over previous
//
#include <hip/hip_runtime.h>
#include <cstddef>

#define NN 50000
#define NE 800000
#define NG 128
#define IND 100
#define HID 256
#define NSTEPS 5
#define PCH 8

typedef __attribute__((ext_vector_type(8))) short bf16x8;   // 8 bf16 = 4 VGPRs
typedef __attribute__((ext_vector_type(4))) float f32x4;

__device__ __forceinline__ float b2f(unsigned h) { return __uint_as_float(h << 16); }
__device__ __forceinline__ unsigned short f2b(float f) {
    unsigned u = __float_as_uint(f);
    unsigned r = (u + 0x7FFFu + ((u >> 16) & 1u)) >> 16;   // RNE
    return (unsigned short)r;
}
__device__ __forceinline__ float sigm(float x) { return 1.f / (1.f + __expf(-x)); }
__device__ __forceinline__ float tanh_fast(float x) { return 1.f - 2.f / (1.f + __expf(2.f * x)); }

// =====================================================================
// bf16 MFMA GEMM: C[M,N](bf16) = act(A[M,K]bf16 @ Bt[N,K]bf16^T + bias)
// BM=BN=128, BK=32. 256 thr = 4 waves (2x2), wave tile 64x64.
// blockIdx.z batching: Bt += z*btz, C += z*cz. If Clo != nullptr, also
// writes the bf16 RESIDUAL (v - b2f(hi)) — hi/lo pair ~ fp32 precision.
// =====================================================================
#define LSTR 40
__global__ __launch_bounds__(256) void gemm_bf16(const unsigned short* __restrict__ A,
                                                 const unsigned short* __restrict__ Bt,
                                                 const float* __restrict__ bias, int act,
                                                 unsigned short* __restrict__ C,
                                                 unsigned short* __restrict__ Clo,
                                                 int M, int N, int K,
                                                 size_t btz, size_t cz)
{
    Bt += (size_t)blockIdx.z * btz;
    C  += (size_t)blockIdx.z * cz;
    __shared__ unsigned short As[128 * LSTR];
    __shared__ unsigned short Bs[128 * LSTR];
    const int tid  = threadIdx.x;
    const int row0 = blockIdx.y * 128;
    const int col0 = blockIdx.x * 128;
    const int wave = tid >> 6, lane = tid & 63;
    const int wm = wave >> 1, wn = wave & 1;
    const int lr = lane & 15, q = lane >> 4;
    const int r_st = tid >> 2;
    const int ks   = tid & 3;

    f32x4 acc[4][4];
    #pragma unroll
    for (int i = 0; i < 4; ++i)
        #pragma unroll
        for (int j = 0; j < 4; ++j) acc[i][j] = (f32x4){0.f, 0.f, 0.f, 0.f};

    for (int k0 = 0; k0 < K; k0 += 32) {
        #pragma unroll
        for (int it = 0; it < 2; ++it) {
            int r  = r_st + it * 64;
            int ga = min(row0 + r, M - 1);
            uint4 av = *(const uint4*)(A + (size_t)ga * K + k0 + ks * 8);
            *(uint4*)(As + r * LSTR + ks * 8) = av;
            uint4 bv = *(const uint4*)(Bt + (size_t)(col0 + r) * K + k0 + ks * 8);
            *(uint4*)(Bs + r * LSTR + ks * 8) = bv;
        }
        __syncthreads();
        bf16x8 af[4], bfr[4];
        #pragma unroll
        for (int i = 0; i < 4; ++i)
            af[i]  = *(const bf16x8*)(As + (wm * 64 + i * 16 + lr) * LSTR + q * 8);
        #pragma unroll
        for (int j = 0; j < 4; ++j)
            bfr[j] = *(const bf16x8*)(Bs + (wn * 64 + j * 16 + lr) * LSTR + q * 8);
        #pragma unroll
        for (int i = 0; i < 4; ++i)
            #pragma unroll
            for (int j = 0; j < 4; ++j)
                acc[i][j] = __builtin_amdgcn_mfma_f32_16x16x32_bf16(af[i], bfr[j], acc[i][j], 0, 0, 0);
        __syncthreads();
    }
    #pragma unroll
    for (int i = 0; i < 4; ++i) {
        int rbase = row0 + wm * 64 + i * 16 + q * 4;
        #pragma unroll
        for (int j = 0; j < 4; ++j) {
            int col = col0 + wn * 64 + j * 16 + lr;
            if (col >= N) continue;
            float badd = bias ? bias[col] : 0.f;
            #pragma unroll
            for (int r = 0; r < 4; ++r) {
                int row = rbase + r;
                if (row < M) {
                    float v = acc[i][j][r] + badd;
                    if (act) v = fmaxf(v, 0.f);
                    unsigned short hi = f2b(v);
                    C[(size_t)row * N + col] = hi;
                    if (Clo) Clo[(size_t)row * N + col] = f2b(v - b2f(hi));
                }
            }
        }
    }
}

// =====================================================================
// Fused GRU v10 = v9 + bf16 hi/lo recurrence state (no fp32 master):
// h = b2f(hi) + b2f(lo) ~ fp32 precision; epilogue writes hi/lo pair
// (4B) instead of fp32 + mirror (6B) -> WRITE 76.8 -> 51.2 MB/step.
// acc merged to 4 sets (r, z share gi+gh accumulators) = 64 AGPRs;
// 64 arch VGPRs -> 128 total = 512/4 -> 4 waves/EU, no spill.
// 64 rows x 64 cols, 4 waves side-by-side. A staged per-32k via LDS w/
// 1-deep prefetch (deeper spills: R7/R10); weights direct global->VGPR.
// =====================================================================
__global__ __launch_bounds__(256, 4) void gru_mfma(const unsigned short* __restrict__ agg,
                                                   const unsigned short* __restrict__ hbf,
                                                   const unsigned short* __restrict__ hlo,
                                                   unsigned short* __restrict__ hbfo,
                                                   unsigned short* __restrict__ hloo,
                                                   const unsigned short* __restrict__ Wgi,
                                                   const unsigned short* __restrict__ Wgh,
                                                   const float* __restrict__ bih,
                                                   const float* __restrict__ bhh,
                                                   int M, int dorelu)
{
    __shared__ unsigned short Sa[64 * LSTR];
    __shared__ unsigned short Sh[64 * LSTR];
    const int tid  = threadIdx.x;
    const int row0 = blockIdx.y * 64;
    const int col0 = blockIdx.x * 64;
    const int wave = tid >> 6, lane = tid & 63;
    const int lr = lane & 15, q = lane >> 4;
    const int cw = col0 + wave * 16;       // this wave's 16 output cols
    const int r_st = tid >> 2, ks = tid & 3;

    // acc sets: 0 = r (agg+hbf), 1 = z (agg+hbf), 2 = i_n (agg), 3 = h_n (hbf)
    f32x4 acc[4][4];
    #pragma unroll
    for (int g = 0; g < 4; ++g)
        #pragma unroll
        for (int i = 0; i < 4; ++i) acc[g][i] = (f32x4){0.f, 0.f, 0.f, 0.f};

    const int ga = min(row0 + r_st, M - 1);
    uint4 pa = *(const uint4*)(agg + (size_t)ga * HID + ks * 8);
    uint4 ph = *(const uint4*)(hbf + (size_t)ga * HID + ks * 8);

    #pragma unroll
    for (int kk = 0; kk < 8; ++kk) {
        const int k0 = kk * 32;
        __syncthreads();
        *(uint4*)(Sa + r_st * LSTR + ks * 8) = pa;
        *(uint4*)(Sh + r_st * LSTR + ks * 8) = ph;
        __syncthreads();
        if (kk < 7) {
            pa = *(const uint4*)(agg + (size_t)ga * HID + k0 + 32 + ks * 8);
            ph = *(const uint4*)(hbf + (size_t)ga * HID + k0 + 32 + ks * 8);
        }
        // 6 weight fragments straight from global (L2-resident)
        bf16x8 wir = *(const bf16x8*)(Wgi + (size_t)(0*HID + cw + lr) * HID + k0 + q * 8);
        bf16x8 wiz = *(const bf16x8*)(Wgi + (size_t)(1*HID + cw + lr) * HID + k0 + q * 8);
        bf16x8 win = *(const bf16x8*)(Wgi + (size_t)(2*HID + cw + lr) * HID + k0 + q * 8);
        bf16x8 whr = *(const bf16x8*)(Wgh + (size_t)(0*HID + cw + lr) * HID + k0 + q * 8);
        bf16x8 whz = *(const bf16x8*)(Wgh + (size_t)(1*HID + cw + lr) * HID + k0 + q * 8);
        bf16x8 whn = *(const bf16x8*)(Wgh + (size_t)(2*HID + cw + lr) * HID + k0 + q * 8);
        bf16x8 afa[4], afh[4];
        #pragma unroll
        for (int i = 0; i < 4; ++i) {
            afa[i] = *(const bf16x8*)(Sa + (i * 16 + lr) * LSTR + q * 8);
            afh[i] = *(const bf16x8*)(Sh + (i * 16 + lr) * LSTR + q * 8);
        }
        #pragma unroll
        for (int i = 0; i < 4; ++i) {
            acc[0][i] = __builtin_amdgcn_mfma_f32_16x16x32_bf16(afa[i], wir, acc[0][i], 0, 0, 0);
            acc[0][i] = __builtin_amdgcn_mfma_f32_16x16x32_bf16(afh[i], whr, acc[0][i], 0, 0, 0);
            acc[1][i] = __builtin_amdgcn_mfma_f32_16x16x32_bf16(afa[i], wiz, acc[1][i], 0, 0, 0);
            acc[1][i] = __builtin_amdgcn_mfma_f32_16x16x32_bf16(afh[i], whz, acc[1][i], 0, 0, 0);
            acc[2][i] = __builtin_amdgcn_mfma_f32_16x16x32_bf16(afa[i], win, acc[2][i], 0, 0, 0);
            acc[3][i] = __builtin_amdgcn_mfma_f32_16x16x32_bf16(afh[i], whn, acc[3][i], 0, 0, 0);
        }
    }

    // epilogue: col cg fixed per lane; biases loaded once
    const int cg = cw + lr;
    const float brr = bih[cg]         + bhh[cg];
    const float bzz = bih[HID + cg]   + bhh[HID + cg];
    const float bin = bih[2*HID + cg];
    const float bhn = bhh[2*HID + cg];
    #pragma unroll
    for (int i = 0; i < 4; ++i) {
        #pragma unroll
        for (int r = 0; r < 4; ++r) {
            int row = row0 + i * 16 + q * 4 + r;
            if (row < M) {
                float rr = sigm(acc[0][i][r] + brr);
                float zz = sigm(acc[1][i][r] + bzz);
                float nn = tanh_fast(acc[2][i][r] + bin + rr * (acc[3][i][r] + bhn));
                size_t off = (size_t)row * HID + cg;
                float hv = b2f(hbf[off]) + b2f(hlo[off]);   // hi/lo ~ fp32
                float o = (1.f - zz) * nn + zz * hv;
                if (dorelu) o = fmaxf(o, 0.f);
                unsigned short hi = f2b(o);
                hbfo[off] = hi;
                hloo[off] = f2b(o - b2f(hi));
            }
        }
    }
}

// ---------- fp32 tiled GEMM (classifier only) ----------
template<int ACT>
__global__ __launch_bounds__(256) void gemm_kn(const float* __restrict__ A,
                                               const float* __restrict__ B,
                                               const float* __restrict__ bias,
                                               float* __restrict__ C,
                                               int M, int N, int K)
{
    __shared__ float As[64][17];
    __shared__ float Bs[16][65];
    const int tid  = threadIdx.x;
    const int row0 = blockIdx.y * 64;
    const int col0 = blockIdx.x * 64;
    const int tr = tid >> 4, tc = tid & 15;
    const int ar = tid >> 2, akq = tid & 3;
    const int bk = tid >> 4, bj = (tid & 15) << 2;

    float acc[4][4] = {};
    for (int k0 = 0; k0 < K; k0 += 16) {
        float4 av = make_float4(0.f,0.f,0.f,0.f);
        if (row0 + ar < M && (k0 + (akq<<2)) < K)
            av = *(const float4*)(A + (size_t)(row0+ar)*K + k0 + (akq<<2));
        As[ar][(akq<<2)+0] = av.x; As[ar][(akq<<2)+1] = av.y;
        As[ar][(akq<<2)+2] = av.z; As[ar][(akq<<2)+3] = av.w;
        float4 bv = make_float4(0.f,0.f,0.f,0.f);
        if (k0 + bk < K)
            bv = *(const float4*)(B + (size_t)(k0+bk)*N + col0 + bj);
        Bs[bk][bj+0] = bv.x; Bs[bk][bj+1] = bv.y; Bs[bk][bj+2] = bv.z; Bs[bk][bj+3] = bv.w;
        __syncthreads();
        #pragma unroll
        for (int k = 0; k < 16; ++k) {
            float a4[4], b4[4];
            #pragma unroll
            for (int i = 0; i < 4; ++i) a4[i] = As[(tr<<2)+i][k];
            #pragma unroll
            for (int j = 0; j < 4; ++j) b4[j] = Bs[k][(tc<<2)+j];
            #pragma unroll
            for (int i = 0; i < 4; ++i)
                #pragma unroll
                for (int j = 0; j < 4; ++j) acc[i][j] += a4[i]*b4[j];
        }
        __syncthreads();
    }
    #pragma unroll
    for (int i = 0; i < 4; ++i) {
        int row = row0 + (tr<<2) + i;
        if (row >= M) continue;
        #pragma unroll
        for (int j = 0; j < 4; ++j) {
            int col = col0 + (tc<<2) + j;
            float v = acc[i][j];
            if (bias) v += bias[col];
            if (ACT == 1) v = fmaxf(v, 0.f);
            C[(size_t)row*N + col] = v;
        }
    }
}

// ---------- CSR build ----------
__global__ void edge_count(const int* __restrict__ dst, int* __restrict__ cnt, int E) {
    int e = blockIdx.x*256 + threadIdx.x;
    if (e < E) atomicAdd(&cnt[dst[e]], 1);
}
__global__ void scan_bsums(const int* __restrict__ cnt, int* __restrict__ bsum, int n) {
    __shared__ int sd[512];
    int tid = threadIdx.x, i = blockIdx.x*512 + tid;
    sd[tid] = (i < n) ? cnt[i] : 0;
    __syncthreads();
    for (int off = 256; off > 0; off >>= 1) {
        if (tid < off) sd[tid] += sd[tid+off];
        __syncthreads();
    }
    if (tid == 0) bsum[blockIdx.x] = sd[0];
}
__global__ void scan_top(int* __restrict__ bsum, int nb) {   // single block, 128 thr
    __shared__ int sd[128];
    int tid = threadIdx.x;
    int v = (tid < nb) ? bsum[tid] : 0;
    sd[tid] = v;
    __syncthreads();
    for (int off = 1; off < 128; off <<= 1) {
        int t = (tid >= off) ? sd[tid-off] : 0;
        __syncthreads();
        sd[tid] += t;
        __syncthreads();
    }
    if (tid < nb) bsum[tid] = sd[tid] - v;   // exclusive
}
__global__ void scan_local(const int* __restrict__ cnt, const int* __restrict__ bsum,
                           int* __restrict__ rp, int n) {
    __shared__ int sd[512];
    int tid = threadIdx.x, i = blockIdx.x*512 + tid;
    int v = (i < n) ? cnt[i] : 0;
    sd[tid] = v;
    __syncthreads();
    for (int off = 1; off < 512; off <<= 1) {
        int t = (tid >= off) ? sd[tid-off] : 0;
        __syncthreads();
        sd[tid] += t;
        __syncthreads();
    }
    if (i < n) rp[i] = bsum[blockIdx.x] + sd[tid] - v;
    if (i == n-1) rp[n] = bsum[blockIdx.x] + sd[tid];
}
__global__ void edge_fill(const int* __restrict__ src, const int* __restrict__ dst,
                          const int* __restrict__ rp, int* __restrict__ cur,
                          int* __restrict__ ci, int E) {
    int e = blockIdx.x*256 + threadIdx.x;
    if (e < E) {
        int d = dst[e];
        int pos = rp[d] + atomicAdd(&cur[d], 1);
        ci[pos] = src[e];
    }
}

// =====================================================================
// gather v3: one wave per node; 32 lanes cover one 512B row (16B/lane),
// wave halves take even/odd neighbors. Single uniform loop processes 16
// neighbors/iter with 8 loads in flight PER LANE; final partial batch is
// predicated (load-or-zero) so low-degree nodes also get 8-deep MLP.
// =====================================================================
__global__ void gather_agg(const unsigned short* __restrict__ m, unsigned short* __restrict__ agg,
                           const int* __restrict__ rp, const int* __restrict__ ci, int M)
{
    int node = blockIdx.x*4 + (threadIdx.x >> 6);
    int lane = threadIdx.x & 63;
    if (node >= M) return;
    const int half = lane >> 5;      // 0: even neighbors, 1: odd
    const int li   = lane & 31;      // 16B slice (8 bf16) within the row
    const int s = rp[node], e = rp[node+1];
    float a[8] = {0.f,0.f,0.f,0.f,0.f,0.f,0.f,0.f};
    for (int p = s; p < e; p += 16) {
        uint4 v[8];
        #pragma unroll
        for (int u = 0; u < 8; ++u) {
            int idx = p + 2*u + half;
            if (idx < e) {
                int r = ci[idx];
                v[u] = *(const uint4*)(m + (size_t)r * HID + li * 8);
            } else {
                v[u] = make_uint4(0u, 0u, 0u, 0u);   // b2f(0) == 0.0f
            }
        }
        #pragma unroll
        for (int u = 0; u < 8; ++u) {
            a[0] += b2f(v[u].x & 0xffffu); a[1] += b2f(v[u].x >> 16);
            a[2] += b2f(v[u].y & 0xffffu); a[3] += b2f(v[u].y >> 16);
            a[4] += b2f(v[u].z & 0xffffu); a[5] += b2f(v[u].z >> 16);
            a[6] += b2f(v[u].w & 0xffffu); a[7] += b2f(v[u].w >> 16);
        }
    }
    #pragma unroll
    for (int u = 0; u < 8; ++u) a[u] += __shfl_xor(a[u], 32, 64);
    if (half == 0) {
        uint4 o;
        o.x = (unsigned)f2b(a[0]) | ((unsigned)f2b(a[1]) << 16);
        o.y = (unsigned)f2b(a[2]) | ((unsigned)f2b(a[3]) << 16);
        o.z = (unsigned)f2b(a[4]) | ((unsigned)f2b(a[5]) << 16);
        o.w = (unsigned)f2b(a[6]) | ((unsigned)f2b(a[7]) << 16);
        *(uint4*)(agg + (size_t)node * HID + li * 8) = o;
    }
}

// ---------- input split-precision prep ----------
// A' row n: cols [0,128) = bf16(x) (hi), cols [128,256) = bf16(x - hi); pad k>=100 with 0
__global__ void split_x(const float* __restrict__ x, unsigned short* __restrict__ A) {
    int n = blockIdx.x, k = threadIdx.x;   // 128 threads
    unsigned short hi = 0, lo = 0;
    if (k < IND) {
        float v = x[(size_t)n * IND + k];
        hi = f2b(v);
        lo = f2b(v - b2f(hi));
    }
    A[(size_t)n * 256 + k]       = hi;
    A[(size_t)n * 256 + 128 + k] = lo;
}
// Bt' row n (output col): cols [0,128) = bf16(W_in[k][n]), cols [128,256) same; pad 0
__global__ void prep_win(const float* __restrict__ w, unsigned short* __restrict__ bt) {
    int n = blockIdx.x, k = threadIdx.x;   // 256 blocks x 128 threads
    unsigned short v = (k < IND) ? f2b(w[(size_t)k * HID + n]) : (unsigned short)0;
    bt[(size_t)n * 256 + k]       = v;
    bt[(size_t)n * 256 + 128 + k] = v;
}

__global__ void cvt_elem(const float* __restrict__ src, unsigned short* __restrict__ dst, int n) {
    int i = blockIdx.x*256 + threadIdx.x;
    if (i < n) dst[i] = f2b(src[i]);
}
// Wa1 [256][128] ([k][n]) -> Wa1t bf16 [128][256] ([n][k])
__global__ void prep_wa1(const float* __restrict__ w, unsigned short* __restrict__ wt) {
    int n = blockIdx.x, k = threadIdx.x;
    wt[(size_t)n*HID + k] = f2b(w[(size_t)k*128 + n]);
}

// ---------- attention scalar head ----------
__global__ void att_sig(const unsigned short* __restrict__ t, const float* __restrict__ Wa2,
                        const float* __restrict__ ba2, float* __restrict__ a, int M)
{
    int node = blockIdx.x*4 + (threadIdx.x >> 6);
    int lane = threadIdx.x & 63;
    if (node >= M) return;
    float s = b2f(t[(size_t)node*128 + lane])*Wa2[lane]
            + b2f(t[(size_t)node*128 + 64 + lane])*Wa2[64+lane];
    #pragma unroll
    for (int off = 32; off > 0; off >>= 1) s += __shfl_down(s, off, 64);
    if (lane == 0) a[node] = 1.f/(1.f+__expf(-(s + ba2[0])));
}

// ---------- pooling, two-phase (reads bf16 h mirror) ----------
__device__ __forceinline__ int lowerb(const int* arr, int n, int val) {
    int lo = 0, hi = n;
    while (lo < hi) { int mid = (lo+hi)>>1; if (arr[mid] < val) lo = mid+1; else hi = mid; }
    return lo;
}
__global__ void pool_partial(const unsigned short* __restrict__ hbf, const float* __restrict__ a,
                             const int* __restrict__ batch, float* __restrict__ part, int M)
{
    int g = blockIdx.x, c = blockIdx.y, j = threadIdx.x;
    int lo = lowerb(batch, M, g);
    int hi = lowerb(batch, M, g+1);
    int len = hi - lo, per = (len + PCH - 1) / PCH;
    int s = lo + c * per, e = min(s + per, hi);
    float sum = 0.f, mx = 0.f;
    for (int n = s; n < e; ++n) {
        float v = b2f(hbf[(size_t)n*HID + j]) * a[n];
        sum += v; mx = fmaxf(mx, v);
    }
    float* pp = part + ((size_t)g*PCH + c) * 512;
    pp[j] = sum; pp[256 + j] = mx;
}
__global__ void pool_final(const float* __restrict__ part, const int* __restrict__ batch,
                           float* __restrict__ gout, int M)
{
    int g = blockIdx.x, j = threadIdx.x;
    float sum = 0.f, mx = 0.f;
    for (int c = 0; c < PCH; ++c) {
        const float* pp = part + ((size_t)g*PCH + c) * 512;
        sum += pp[j];
        mx = fmaxf(mx, pp[256 + j]);
    }
    int lo = lowerb(batch, M, g);
    int hi = lowerb(batch, M, g+1);
    float cnt = (float)(hi - lo);
    gout[(size_t)g*512 + j]       = sum / fmaxf(cnt, 1.f);
    gout[(size_t)g*512 + 256 + j] = mx;   // wx >= 0 so 0-init == where(count>0,max,0)
}

__global__ void preds_kernel(const float* __restrict__ g2, const float* __restrict__ W,
                             const float* __restrict__ b, float* __restrict__ out)
{
    int t = threadIdx.x;
    int row = t >> 1, col = t & 1;
    float s = b[col];
    for (int k = 0; k < 128; ++k) s += g2[row*128 + k] * W[k*2 + col];
    out[row*2 + col] = s;
}

extern "C" void kernel_launch(void* const* d_in, const int* in_sizes, int n_in,
                              void* d_out, int out_size, void* d_ws, size_t ws_size,
                              hipStream_t stream)
{
    const float* x     = (const float*)d_in[0];
    const int*   eidx  = (const int*)  d_in[1];
    const int*   batch = (const int*)  d_in[2];
    const float* W_in  = (const float*)d_in[3];
    const float* b_in  = (const float*)d_in[4];
    const float* ggc_w = (const float*)d_in[5];
    const float* W_ih  = (const float*)d_in[6];
    const float* W_hh  = (const float*)d_in[7];
    const float* b_ih  = (const float*)d_in[8];
    const float* b_hh  = (const float*)d_in[9];
    const float* Wa1   = (const float*)d_in[10];
    const float* ba1   = (const float*)d_in[11];
    const float* Wa2   = (const float*)d_in[12];
    const float* ba2   = (const float*)d_in[13];
    const float* Wc1   = (const float*)d_in[14];
    const float* bc1   = (const float*)d_in[15];
    const float* Wc2   = (const float*)d_in[16];
    const float* bc2   = (const float*)d_in[17];
    const float* Wc3   = (const float*)d_in[18];
    const float* bc3   = (const float*)d_in[19];

    float* out  = (float*)d_out;
    float* aout = out + NG*2;

    // ---- workspace layout (~112 MB; known-safe budget 158 MB) ----
    char* p = (char*)d_ws;
    auto alloc = [&](size_t bytes) -> char* {
        char* r = p; p += (bytes + 255) & ~(size_t)255; return r;
    };
    unsigned short* hbfP  = (unsigned short*)alloc((size_t)NN*HID*2);  // 25.6 MB (hi)
    unsigned short* hbfQ  = (unsigned short*)alloc((size_t)NN*HID*2);  // 25.6 MB (hi, aliased as split-x A')
    unsigned short* hloP  = (unsigned short*)alloc((size_t)NN*HID*2);  // 25.6 MB (lo residual)
    unsigned short* hloQ  = (unsigned short*)alloc((size_t)NN*HID*2);  // 25.6 MB
    unsigned short* aggbf = (unsigned short*)alloc((size_t)NN*HID*2);  // 25.6 MB (reused as tbuf)
    int* row_ptr = (int*)alloc((NN+1)*4);
    int* cursor  = (int*)alloc(NN*4);
    int* col_idx = (int*)alloc((size_t)NE*4);
    int* bsum    = (int*)alloc(128*4);
    unsigned short* wgbf   = (unsigned short*)alloc((size_t)NSTEPS*HID*HID*2);  // ggc_w bf16
    unsigned short* WihBf  = (unsigned short*)alloc((size_t)768*HID*2);
    unsigned short* WhhBf  = (unsigned short*)alloc((size_t)768*HID*2);
    unsigned short* WcombT = (unsigned short*)alloc((size_t)NSTEPS*768*HID*2);  // 2.0 MB
    unsigned short* Wa1t   = (unsigned short*)alloc((size_t)128*HID*2);
    unsigned short* WinT   = (unsigned short*)alloc((size_t)256*256*2);
    float* part = (float*)alloc((size_t)NG*PCH*512*4);
    float* gbuf = (float*)alloc((size_t)NG*2*HID*4);
    float* g1   = (float*)alloc((size_t)NG*HID*4);
    float* g2   = (float*)alloc((size_t)NG*128*4);

    const int* esrc = eidx;
    const int* edst = eidx + NE;
    dim3 blk(256);
    const int NB512 = (NN + 511) / 512;   // 98

    // CSR build
    hipMemsetAsync(cursor, 0, NN*sizeof(int), stream);
    edge_count<<<NE/256, blk, 0, stream>>>(edst, cursor, NE);
    scan_bsums<<<NB512, 512, 0, stream>>>(cursor, bsum, NN);
    scan_top<<<1, 128, 0, stream>>>(bsum, NB512);
    scan_local<<<NB512, 512, 0, stream>>>(cursor, bsum, row_ptr, NN);
    hipMemsetAsync(cursor, 0, NN*sizeof(int), stream);
    edge_fill<<<NE/256, blk, 0, stream>>>(esrc, edst, row_ptr, cursor, col_idx, NE);

    // weight prep (bf16) + combined gi weights: WcombT_s = Wih @ w_s^T, batched over s
    cvt_elem<<<(NSTEPS*HID*HID + 255)/256, blk, 0, stream>>>(ggc_w, wgbf, NSTEPS*HID*HID);
    cvt_elem<<<768, blk, 0, stream>>>(W_ih, WihBf, 768*HID);
    cvt_elem<<<768, blk, 0, stream>>>(W_hh, WhhBf, 768*HID);
    prep_wa1<<<128, blk, 0, stream>>>(Wa1, Wa1t);
    gemm_bf16<<<dim3(2, 6, NSTEPS), blk, 0, stream>>>(
        WihBf, wgbf, nullptr, 0, WcombT, nullptr, 768, HID, HID,
        (size_t)HID*HID, (size_t)768*HID);

    // input projection via split-precision bf16 MFMA:
    //   A' = [bf16(x) | bf16(x - hi)] (K=256), B' = [W_hi | W_hi]
    // Writes hi -> hbfP and lo residual -> hloP. A' aliases hbfQ.
    unsigned short* Ax = hbfQ;
    split_x<<<NN, 128, 0, stream>>>(x, Ax);
    prep_win<<<256, 128, 0, stream>>>(W_in, WinT);
    gemm_bf16<<<dim3(2, (NN+127)/128), blk, 0, stream>>>(
        Ax, WinT, b_in, 1, hbfP, hloP, NN, HID, 256, 0, 0);

    // 5 steps: gather h -> agg_h; gru with combined gi weights (no m-GEMM).
    // Last step fuses the post-loop relu into the gru epilogue.
    unsigned short* hbf  = hbfP;  unsigned short* hlo  = hloP;
    unsigned short* hbfn = hbfQ;  unsigned short* hlon = hloQ;
    const int MB64 = (NN + 63) / 64;   // 782
    for (int s = 0; s < NSTEPS; ++s) {
        gather_agg<<<NN/4, blk, 0, stream>>>(hbf, aggbf, row_ptr, col_idx, NN);
        gru_mfma<<<dim3(HID/64, MB64), blk, 0, stream>>>(
            aggbf, hbf, hlo, hbfn, hlon, WcombT + (size_t)s*768*HID, WhhBf, b_ih, b_hh,
            NN, (s == NSTEPS-1) ? 1 : 0);
        { unsigned short* t0 = hbf; hbf = hbfn; hbfn = t0; }
        { unsigned short* t1 = hlo; hlo = hlon; hlon = t1; }
    }
    // hbf holds bf16 relu(h5); hlo its residual (unused downstream).

    // attention: t = relu(h @ Wa1 + ba1) [bf16, reuses aggbf], a = sigmoid(t @ Wa2 + ba2)
    unsigned short* tbuf = aggbf;
    gemm_bf16<<<dim3(1, (NN+127)/128), blk, 0, stream>>>(hbf, Wa1t, ba1, 1, tbuf, nullptr, NN, 128, HID, 0, 0);
    att_sig<<<NN/4, blk, 0, stream>>>(tbuf, Wa2, ba2, aout, NN);

    // pooling -> g [128, 512] (two-phase, bf16 h mirror)
    pool_partial<<<dim3(NG, PCH), blk, 0, stream>>>(hbf, aout, batch, part, NN);
    pool_final<<<NG, blk, 0, stream>>>(part, batch, gbuf, NN);

    // classifier (fp32, tiny)
    gemm_kn<1><<<dim3(HID/64, (NG+63)/64), blk, 0, stream>>>(gbuf, Wc1, bc1, g1, NG, HID, 2*HID);
    gemm_kn<1><<<dim3(2,      (NG+63)/64), blk, 0, stream>>>(g1,   Wc2, bc2, g2, NG, 128, HID);
    preds_kernel<<<1, blk, 0, stream>>>(g2, Wc3, bc3, out);
}

// Round 15
// 1187.840 us; speedup vs baseline: 1.0463x; 1.0396x over previous
//
#include <hip/hip_runtime.h>
#include <cstddef>

#define NN 50000
#define NE 800000
#define NG 128
#define IND 100
#define HID 256
#define NSTEPS 5
#define PCH 8

typedef __attribute__((ext_vector_type(8))) short bf16x8;   // 8 bf16 = 4 VGPRs
typedef __attribute__((ext_vector_type(4))) float f32x4;

__device__ __forceinline__ float b2f(unsigned h) { return __uint_as_float(h << 16); }
__device__ __forceinline__ unsigned short f2b(float f) {
    unsigned u = __float_as_uint(f);
    unsigned r = (u + 0x7FFFu + ((u >> 16) & 1u)) >> 16;   // RNE
    return (unsigned short)r;
}
__device__ __forceinline__ float sigm(float x) { return 1.f / (1.f + __expf(-x)); }
__device__ __forceinline__ float tanh_fast(float x) { return 1.f - 2.f / (1.f + __expf(2.f * x)); }

// =====================================================================
// bf16 MFMA GEMM: C[M,N](bf16) = act(A[M,K]bf16 @ Bt[N,K]bf16^T + bias)
// BM=BN=128, BK=32. 256 thr = 4 waves (2x2), wave tile 64x64.
// blockIdx.z batching: Bt += z*btz, C += z*cz. If Clo != nullptr, also
// writes the bf16 RESIDUAL (v - b2f(hi)) — hi/lo pair ~ fp32 precision.
// =====================================================================
#define LSTR 40
__global__ __launch_bounds__(256) void gemm_bf16(const unsigned short* __restrict__ A,
                                                 const unsigned short* __restrict__ Bt,
                                                 const float* __restrict__ bias, int act,
                                                 unsigned short* __restrict__ C,
                                                 unsigned short* __restrict__ Clo,
                                                 int M, int N, int K,
                                                 size_t btz, size_t cz)
{
    Bt += (size_t)blockIdx.z * btz;
    C  += (size_t)blockIdx.z * cz;
    __shared__ unsigned short As[128 * LSTR];
    __shared__ unsigned short Bs[128 * LSTR];
    const int tid  = threadIdx.x;
    const int row0 = blockIdx.y * 128;
    const int col0 = blockIdx.x * 128;
    const int wave = tid >> 6, lane = tid & 63;
    const int wm = wave >> 1, wn = wave & 1;
    const int lr = lane & 15, q = lane >> 4;
    const int r_st = tid >> 2;
    const int ks   = tid & 3;

    f32x4 acc[4][4];
    #pragma unroll
    for (int i = 0; i < 4; ++i)
        #pragma unroll
        for (int j = 0; j < 4; ++j) acc[i][j] = (f32x4){0.f, 0.f, 0.f, 0.f};

    for (int k0 = 0; k0 < K; k0 += 32) {
        #pragma unroll
        for (int it = 0; it < 2; ++it) {
            int r  = r_st + it * 64;
            int ga = min(row0 + r, M - 1);
            uint4 av = *(const uint4*)(A + (size_t)ga * K + k0 + ks * 8);
            *(uint4*)(As + r * LSTR + ks * 8) = av;
            uint4 bv = *(const uint4*)(Bt + (size_t)(col0 + r) * K + k0 + ks * 8);
            *(uint4*)(Bs + r * LSTR + ks * 8) = bv;
        }
        __syncthreads();
        bf16x8 af[4], bfr[4];
        #pragma unroll
        for (int i = 0; i < 4; ++i)
            af[i]  = *(const bf16x8*)(As + (wm * 64 + i * 16 + lr) * LSTR + q * 8);
        #pragma unroll
        for (int j = 0; j < 4; ++j)
            bfr[j] = *(const bf16x8*)(Bs + (wn * 64 + j * 16 + lr) * LSTR + q * 8);
        #pragma unroll
        for (int i = 0; i < 4; ++i)
            #pragma unroll
            for (int j = 0; j < 4; ++j)
                acc[i][j] = __builtin_amdgcn_mfma_f32_16x16x32_bf16(af[i], bfr[j], acc[i][j], 0, 0, 0);
        __syncthreads();
    }
    #pragma unroll
    for (int i = 0; i < 4; ++i) {
        int rbase = row0 + wm * 64 + i * 16 + q * 4;
        #pragma unroll
        for (int j = 0; j < 4; ++j) {
            int col = col0 + wn * 64 + j * 16 + lr;
            if (col >= N) continue;
            float badd = bias ? bias[col] : 0.f;
            #pragma unroll
            for (int r = 0; r < 4; ++r) {
                int row = rbase + r;
                if (row < M) {
                    float v = acc[i][j][r] + badd;
                    if (act) v = fmaxf(v, 0.f);
                    unsigned short hi = f2b(v);
                    C[(size_t)row * N + col] = hi;
                    if (Clo) Clo[(size_t)row * N + col] = f2b(v - b2f(hi));
                }
            }
        }
    }
}

// =====================================================================
// Fused GRU v11 = v10 + LDS ping-pong double-buffer (1 barrier/iter,
// was 2). Two 64x32k buffers (20 KB total; 4 blocks/CU -> 80 KB LDS).
// Register lifetime of the A-prefetch stays 1 iteration (no spill —
// R7/R10 rule). bf16 hi/lo recurrence state; acc merged to 4 sets =
// 64 AGPRs; 128 total regs = 512/4 -> 4 waves/EU.
// =====================================================================
__global__ __launch_bounds__(256, 4) void gru_mfma(const unsigned short* __restrict__ agg,
                                                   const unsigned short* __restrict__ hbf,
                                                   const unsigned short* __restrict__ hlo,
                                                   unsigned short* __restrict__ hbfo,
                                                   unsigned short* __restrict__ hloo,
                                                   const unsigned short* __restrict__ Wgi,
                                                   const unsigned short* __restrict__ Wgh,
                                                   const float* __restrict__ bih,
                                                   const float* __restrict__ bhh,
                                                   int M, int dorelu)
{
    __shared__ unsigned short Sa[2][64 * LSTR];
    __shared__ unsigned short Sh[2][64 * LSTR];
    const int tid  = threadIdx.x;
    const int row0 = blockIdx.y * 64;
    const int col0 = blockIdx.x * 64;
    const int wave = tid >> 6, lane = tid & 63;
    const int lr = lane & 15, q = lane >> 4;
    const int cw = col0 + wave * 16;       // this wave's 16 output cols
    const int r_st = tid >> 2, ks = tid & 3;

    // acc sets: 0 = r (agg+hbf), 1 = z (agg+hbf), 2 = i_n (agg), 3 = h_n (hbf)
    f32x4 acc[4][4];
    #pragma unroll
    for (int g = 0; g < 4; ++g)
        #pragma unroll
        for (int i = 0; i < 4; ++i) acc[g][i] = (f32x4){0.f, 0.f, 0.f, 0.f};

    const int ga = min(row0 + r_st, M - 1);
    const size_t ab = (size_t)ga * HID + ks * 8;
    // prologue: chunk 0 -> buf 0; chunk 1 -> regs
    {
        uint4 a0 = *(const uint4*)(agg + ab);
        uint4 h0 = *(const uint4*)(hbf + ab);
        *(uint4*)(Sa[0] + r_st * LSTR + ks * 8) = a0;
        *(uint4*)(Sh[0] + r_st * LSTR + ks * 8) = h0;
    }
    uint4 pa = *(const uint4*)(agg + ab + 32);
    uint4 ph = *(const uint4*)(hbf + ab + 32);

    #pragma unroll
    for (int kk = 0; kk < 8; ++kk) {
        const int cur = kk & 1;
        const int k0 = kk * 32;
        __syncthreads();   // prior writes to Sa[cur]/Sh[cur] visible; prior reads of S[cur^1] done
        if (kk < 7) {
            *(uint4*)(Sa[cur ^ 1] + r_st * LSTR + ks * 8) = pa;
            *(uint4*)(Sh[cur ^ 1] + r_st * LSTR + ks * 8) = ph;
        }
        if (kk < 6) {
            pa = *(const uint4*)(agg + ab + k0 + 64);
            ph = *(const uint4*)(hbf + ab + k0 + 64);
        }
        // 6 weight fragments straight from global (L2-resident)
        bf16x8 wir = *(const bf16x8*)(Wgi + (size_t)(0*HID + cw + lr) * HID + k0 + q * 8);
        bf16x8 wiz = *(const bf16x8*)(Wgi + (size_t)(1*HID + cw + lr) * HID + k0 + q * 8);
        bf16x8 win = *(const bf16x8*)(Wgi + (size_t)(2*HID + cw + lr) * HID + k0 + q * 8);
        bf16x8 whr = *(const bf16x8*)(Wgh + (size_t)(0*HID + cw + lr) * HID + k0 + q * 8);
        bf16x8 whz = *(const bf16x8*)(Wgh + (size_t)(1*HID + cw + lr) * HID + k0 + q * 8);
        bf16x8 whn = *(const bf16x8*)(Wgh + (size_t)(2*HID + cw + lr) * HID + k0 + q * 8);
        bf16x8 afa[4], afh[4];
        #pragma unroll
        for (int i = 0; i < 4; ++i) {
            afa[i] = *(const bf16x8*)(Sa[cur] + (i * 16 + lr) * LSTR + q * 8);
            afh[i] = *(const bf16x8*)(Sh[cur] + (i * 16 + lr) * LSTR + q * 8);
        }
        #pragma unroll
        for (int i = 0; i < 4; ++i) {
            acc[0][i] = __builtin_amdgcn_mfma_f32_16x16x32_bf16(afa[i], wir, acc[0][i], 0, 0, 0);
            acc[0][i] = __builtin_amdgcn_mfma_f32_16x16x32_bf16(afh[i], whr, acc[0][i], 0, 0, 0);
            acc[1][i] = __builtin_amdgcn_mfma_f32_16x16x32_bf16(afa[i], wiz, acc[1][i], 0, 0, 0);
            acc[1][i] = __builtin_amdgcn_mfma_f32_16x16x32_bf16(afh[i], whz, acc[1][i], 0, 0, 0);
            acc[2][i] = __builtin_amdgcn_mfma_f32_16x16x32_bf16(afa[i], win, acc[2][i], 0, 0, 0);
            acc[3][i] = __builtin_amdgcn_mfma_f32_16x16x32_bf16(afh[i], whn, acc[3][i], 0, 0, 0);
        }
    }

    // epilogue: col cg fixed per lane; biases loaded once
    const int cg = cw + lr;
    const float brr = bih[cg]         + bhh[cg];
    const float bzz = bih[HID + cg]   + bhh[HID + cg];
    const float bin = bih[2*HID + cg];
    const float bhn = bhh[2*HID + cg];
    #pragma unroll
    for (int i = 0; i < 4; ++i) {
        #pragma unroll
        for (int r = 0; r < 4; ++r) {
            int row = row0 + i * 16 + q * 4 + r;
            if (row < M) {
                float rr = sigm(acc[0][i][r] + brr);
                float zz = sigm(acc[1][i][r] + bzz);
                float nn = tanh_fast(acc[2][i][r] + bin + rr * (acc[3][i][r] + bhn));
                size_t off = (size_t)row * HID + cg;
                float hv = b2f(hbf[off]) + b2f(hlo[off]);   // hi/lo ~ fp32
                float o = (1.f - zz) * nn + zz * hv;
                if (dorelu) o = fmaxf(o, 0.f);
                unsigned short hi = f2b(o);
                hbfo[off] = hi;
                hloo[off] = f2b(o - b2f(hi));
            }
        }
    }
}

// ---------- fp32 tiled GEMM (classifier only) ----------
template<int ACT>
__global__ __launch_bounds__(256) void gemm_kn(const float* __restrict__ A,
                                               const float* __restrict__ B,
                                               const float* __restrict__ bias,
                                               float* __restrict__ C,
                                               int M, int N, int K)
{
    __shared__ float As[64][17];
    __shared__ float Bs[16][65];
    const int tid  = threadIdx.x;
    const int row0 = blockIdx.y * 64;
    const int col0 = blockIdx.x * 64;
    const int tr = tid >> 4, tc = tid & 15;
    const int ar = tid >> 2, akq = tid & 3;
    const int bk = tid >> 4, bj = (tid & 15) << 2;

    float acc[4][4] = {};
    for (int k0 = 0; k0 < K; k0 += 16) {
        float4 av = make_float4(0.f,0.f,0.f,0.f);
        if (row0 + ar < M && (k0 + (akq<<2)) < K)
            av = *(const float4*)(A + (size_t)(row0+ar)*K + k0 + (akq<<2));
        As[ar][(akq<<2)+0] = av.x; As[ar][(akq<<2)+1] = av.y;
        As[ar][(akq<<2)+2] = av.z; As[ar][(akq<<2)+3] = av.w;
        float4 bv = make_float4(0.f,0.f,0.f,0.f);
        if (k0 + bk < K)
            bv = *(const float4*)(B + (size_t)(k0+bk)*N + col0 + bj);
        Bs[bk][bj+0] = bv.x; Bs[bk][bj+1] = bv.y; Bs[bk][bj+2] = bv.z; Bs[bk][bj+3] = bv.w;
        __syncthreads();
        #pragma unroll
        for (int k = 0; k < 16; ++k) {
            float a4[4], b4[4];
            #pragma unroll
            for (int i = 0; i < 4; ++i) a4[i] = As[(tr<<2)+i][k];
            #pragma unroll
            for (int j = 0; j < 4; ++j) b4[j] = Bs[k][(tc<<2)+j];
            #pragma unroll
            for (int i = 0; i < 4; ++i)
                #pragma unroll
                for (int j = 0; j < 4; ++j) acc[i][j] += a4[i]*b4[j];
        }
        __syncthreads();
    }
    #pragma unroll
    for (int i = 0; i < 4; ++i) {
        int row = row0 + (tr<<2) + i;
        if (row >= M) continue;
        #pragma unroll
        for (int j = 0; j < 4; ++j) {
            int col = col0 + (tc<<2) + j;
            float v = acc[i][j];
            if (bias) v += bias[col];
            if (ACT == 1) v = fmaxf(v, 0.f);
            C[(size_t)row*N + col] = v;
        }
    }
}

// ---------- CSR build ----------
__global__ void edge_count(const int* __restrict__ dst, int* __restrict__ cnt, int E) {
    int e = blockIdx.x*256 + threadIdx.x;
    if (e < E) atomicAdd(&cnt[dst[e]], 1);
}
__global__ void scan_bsums(const int* __restrict__ cnt, int* __restrict__ bsum, int n) {
    __shared__ int sd[512];
    int tid = threadIdx.x, i = blockIdx.x*512 + tid;
    sd[tid] = (i < n) ? cnt[i] : 0;
    __syncthreads();
    for (int off = 256; off > 0; off >>= 1) {
        if (tid < off) sd[tid] += sd[tid+off];
        __syncthreads();
    }
    if (tid == 0) bsum[blockIdx.x] = sd[0];
}
__global__ void scan_top(int* __restrict__ bsum, int nb) {   // single block, 128 thr
    __shared__ int sd[128];
    int tid = threadIdx.x;
    int v = (tid < nb) ? bsum[tid] : 0;
    sd[tid] = v;
    __syncthreads();
    for (int off = 1; off < 128; off <<= 1) {
        int t = (tid >= off) ? sd[tid-off] : 0;
        __syncthreads();
        sd[tid] += t;
        __syncthreads();
    }
    if (tid < nb) bsum[tid] = sd[tid] - v;   // exclusive
}
__global__ void scan_local(const int* __restrict__ cnt, const int* __restrict__ bsum,
                           int* __restrict__ rp, int n) {
    __shared__ int sd[512];
    int tid = threadIdx.x, i = blockIdx.x*512 + tid;
    int v = (i < n) ? cnt[i] : 0;
    sd[tid] = v;
    __syncthreads();
    for (int off = 1; off < 512; off <<= 1) {
        int t = (tid >= off) ? sd[tid-off] : 0;
        __syncthreads();
        sd[tid] += t;
        __syncthreads();
    }
    if (i < n) rp[i] = bsum[blockIdx.x] + sd[tid] - v;
    if (i == n-1) rp[n] = bsum[blockIdx.x] + sd[tid];
}
__global__ void edge_fill(const int* __restrict__ src, const int* __restrict__ dst,
                          const int* __restrict__ rp, int* __restrict__ cur,
                          int* __restrict__ ci, int E) {
    int e = blockIdx.x*256 + threadIdx.x;
    if (e < E) {
        int d = dst[e];
        int pos = rp[d] + atomicAdd(&cur[d], 1);
        ci[pos] = src[e];
    }
}

// =====================================================================
// gather v4: one wave per node; 32 lanes cover one 512B row (16B/lane),
// wave halves take even/odd neighbors. 16 neighbors/iter, 8 row-loads in
// flight per lane (predicated); ci indices for the NEXT batch are
// prefetched into registers during the current batch's accumulate so the
// ci->row dependency never sits on the critical path.
// =====================================================================
__global__ void gather_agg(const unsigned short* __restrict__ m, unsigned short* __restrict__ agg,
                           const int* __restrict__ rp, const int* __restrict__ ci, int M)
{
    int node = blockIdx.x*4 + (threadIdx.x >> 6);
    int lane = threadIdx.x & 63;
    if (node >= M) return;
    const int half = lane >> 5;      // 0: even neighbors, 1: odd
    const int li   = lane & 31;      // 16B slice (8 bf16) within the row
    const int s = rp[node], e = rp[node+1];
    float a[8] = {0.f,0.f,0.f,0.f,0.f,0.f,0.f,0.f};
    int cidx[8];
    #pragma unroll
    for (int u = 0; u < 8; ++u) {
        int idx = s + 2*u + half;
        cidx[u] = (idx < e) ? ci[idx] : -1;
    }
    for (int p = s; p < e; p += 16) {
        uint4 v[8];
        #pragma unroll
        for (int u = 0; u < 8; ++u)
            v[u] = (cidx[u] >= 0) ? *(const uint4*)(m + (size_t)cidx[u] * HID + li * 8)
                                  : make_uint4(0u, 0u, 0u, 0u);
        // prefetch next batch's indices (overlaps the accumulate below)
        #pragma unroll
        for (int u = 0; u < 8; ++u) {
            int idx = p + 16 + 2*u + half;
            cidx[u] = (idx < e) ? ci[idx] : -1;
        }
        #pragma unroll
        for (int u = 0; u < 8; ++u) {
            a[0] += b2f(v[u].x & 0xffffu); a[1] += b2f(v[u].x >> 16);
            a[2] += b2f(v[u].y & 0xffffu); a[3] += b2f(v[u].y >> 16);
            a[4] += b2f(v[u].z & 0xffffu); a[5] += b2f(v[u].z >> 16);
            a[6] += b2f(v[u].w & 0xffffu); a[7] += b2f(v[u].w >> 16);
        }
    }
    #pragma unroll
    for (int u = 0; u < 8; ++u) a[u] += __shfl_xor(a[u], 32, 64);
    if (half == 0) {
        uint4 o;
        o.x = (unsigned)f2b(a[0]) | ((unsigned)f2b(a[1]) << 16);
        o.y = (unsigned)f2b(a[2]) | ((unsigned)f2b(a[3]) << 16);
        o.z = (unsigned)f2b(a[4]) | ((unsigned)f2b(a[5]) << 16);
        o.w = (unsigned)f2b(a[6]) | ((unsigned)f2b(a[7]) << 16);
        *(uint4*)(agg + (size_t)node * HID + li * 8) = o;
    }
}

// ---------- input split-precision prep ----------
// A' row n: cols [0,128) = bf16(x) (hi), cols [128,256) = bf16(x - hi); pad k>=100 with 0
__global__ void split_x(const float* __restrict__ x, unsigned short* __restrict__ A) {
    int n = blockIdx.x, k = threadIdx.x;   // 128 threads
    unsigned short hi = 0, lo = 0;
    if (k < IND) {
        float v = x[(size_t)n * IND + k];
        hi = f2b(v);
        lo = f2b(v - b2f(hi));
    }
    A[(size_t)n * 256 + k]       = hi;
    A[(size_t)n * 256 + 128 + k] = lo;
}
// Bt' row n (output col): cols [0,128) = bf16(W_in[k][n]), cols [128,256) same; pad 0
__global__ void prep_win(const float* __restrict__ w, unsigned short* __restrict__ bt) {
    int n = blockIdx.x, k = threadIdx.x;   // 256 blocks x 128 threads
    unsigned short v = (k < IND) ? f2b(w[(size_t)k * HID + n]) : (unsigned short)0;
    bt[(size_t)n * 256 + k]       = v;
    bt[(size_t)n * 256 + 128 + k] = v;
}

__global__ void cvt_elem(const float* __restrict__ src, unsigned short* __restrict__ dst, int n) {
    int i = blockIdx.x*256 + threadIdx.x;
    if (i < n) dst[i] = f2b(src[i]);
}
// Wa1 [256][128] ([k][n]) -> Wa1t bf16 [128][256] ([n][k])
__global__ void prep_wa1(const float* __restrict__ w, unsigned short* __restrict__ wt) {
    int n = blockIdx.x, k = threadIdx.x;
    wt[(size_t)n*HID + k] = f2b(w[(size_t)k*128 + n]);
}

// ---------- attention scalar head ----------
__global__ void att_sig(const unsigned short* __restrict__ t, const float* __restrict__ Wa2,
                        const float* __restrict__ ba2, float* __restrict__ a, int M)
{
    int node = blockIdx.x*4 + (threadIdx.x >> 6);
    int lane = threadIdx.x & 63;
    if (node >= M) return;
    float s = b2f(t[(size_t)node*128 + lane])*Wa2[lane]
            + b2f(t[(size_t)node*128 + 64 + lane])*Wa2[64+lane];
    #pragma unroll
    for (int off = 32; off > 0; off >>= 1) s += __shfl_down(s, off, 64);
    if (lane == 0) a[node] = 1.f/(1.f+__expf(-(s + ba2[0])));
}

// ---------- pooling, two-phase (reads bf16 h mirror) ----------
__device__ __forceinline__ int lowerb(const int* arr, int n, int val) {
    int lo = 0, hi = n;
    while (lo < hi) { int mid = (lo+hi)>>1; if (arr[mid] < val) lo = mid+1; else hi = mid; }
    return lo;
}
__global__ void pool_partial(const unsigned short* __restrict__ hbf, const float* __restrict__ a,
                             const int* __restrict__ batch, float* __restrict__ part, int M)
{
    int g = blockIdx.x, c = blockIdx.y, j = threadIdx.x;
    int lo = lowerb(batch, M, g);
    int hi = lowerb(batch, M, g+1);
    int len = hi - lo, per = (len + PCH - 1) / PCH;
    int s = lo + c * per, e = min(s + per, hi);
    float sum = 0.f, mx = 0.f;
    for (int n = s; n < e; ++n) {
        float v = b2f(hbf[(size_t)n*HID + j]) * a[n];
        sum += v; mx = fmaxf(mx, v);
    }
    float* pp = part + ((size_t)g*PCH + c) * 512;
    pp[j] = sum; pp[256 + j] = mx;
}
__global__ void pool_final(const float* __restrict__ part, const int* __restrict__ batch,
                           float* __restrict__ gout, int M)
{
    int g = blockIdx.x, j = threadIdx.x;
    float sum = 0.f, mx = 0.f;
    for (int c = 0; c < PCH; ++c) {
        const float* pp = part + ((size_t)g*PCH + c) * 512;
        sum += pp[j];
        mx = fmaxf(mx, pp[256 + j]);
    }
    int lo = lowerb(batch, M, g);
    int hi = lowerb(batch, M, g+1);
    float cnt = (float)(hi - lo);
    gout[(size_t)g*512 + j]       = sum / fmaxf(cnt, 1.f);
    gout[(size_t)g*512 + 256 + j] = mx;   // wx >= 0 so 0-init == where(count>0,max,0)
}

__global__ void preds_kernel(const float* __restrict__ g2, const float* __restrict__ W,
                             const float* __restrict__ b, float* __restrict__ out)
{
    int t = threadIdx.x;
    int row = t >> 1, col = t & 1;
    float s = b[col];
    for (int k = 0; k < 128; ++k) s += g2[row*128 + k] * W[k*2 + col];
    out[row*2 + col] = s;
}

extern "C" void kernel_launch(void* const* d_in, const int* in_sizes, int n_in,
                              void* d_out, int out_size, void* d_ws, size_t ws_size,
                              hipStream_t stream)
{
    const float* x     = (const float*)d_in[0];
    const int*   eidx  = (const int*)  d_in[1];
    const int*   batch = (const int*)  d_in[2];
    const float* W_in  = (const float*)d_in[3];
    const float* b_in  = (const float*)d_in[4];
    const float* ggc_w = (const float*)d_in[5];
    const float* W_ih  = (const float*)d_in[6];
    const float* W_hh  = (const float*)d_in[7];
    const float* b_ih  = (const float*)d_in[8];
    const float* b_hh  = (const float*)d_in[9];
    const float* Wa1   = (const float*)d_in[10];
    const float* ba1   = (const float*)d_in[11];
    const float* Wa2   = (const float*)d_in[12];
    const float* ba2   = (const float*)d_in[13];
    const float* Wc1   = (const float*)d_in[14];
    const float* bc1   = (const float*)d_in[15];
    const float* Wc2   = (const float*)d_in[16];
    const float* bc2   = (const float*)d_in[17];
    const float* Wc3   = (const float*)d_in[18];
    const float* bc3   = (const float*)d_in[19];

    float* out  = (float*)d_out;
    float* aout = out + NG*2;

    // ---- workspace layout (~112 MB; known-safe budget 158 MB) ----
    char* p = (char*)d_ws;
    auto alloc = [&](size_t bytes) -> char* {
        char* r = p; p += (bytes + 255) & ~(size_t)255; return r;
    };
    unsigned short* hbfP  = (unsigned short*)alloc((size_t)NN*HID*2);  // 25.6 MB (hi)
    unsigned short* hbfQ  = (unsigned short*)alloc((size_t)NN*HID*2);  // 25.6 MB (hi, aliased as split-x A')
    unsigned short* hloP  = (unsigned short*)alloc((size_t)NN*HID*2);  // 25.6 MB (lo residual)
    unsigned short* hloQ  = (unsigned short*)alloc((size_t)NN*HID*2);  // 25.6 MB
    unsigned short* aggbf = (unsigned short*)alloc((size_t)NN*HID*2);  // 25.6 MB (reused as tbuf)
    int* row_ptr = (int*)alloc((NN+1)*4);
    int* cursor  = (int*)alloc(NN*4);
    int* col_idx = (int*)alloc((size_t)NE*4);
    int* bsum    = (int*)alloc(128*4);
    unsigned short* wgbf   = (unsigned short*)alloc((size_t)NSTEPS*HID*HID*2);  // ggc_w bf16
    unsigned short* WihBf  = (unsigned short*)alloc((size_t)768*HID*2);
    unsigned short* WhhBf  = (unsigned short*)alloc((size_t)768*HID*2);
    unsigned short* WcombT = (unsigned short*)alloc((size_t)NSTEPS*768*HID*2);  // 2.0 MB
    unsigned short* Wa1t   = (unsigned short*)alloc((size_t)128*HID*2);
    unsigned short* WinT   = (unsigned short*)alloc((size_t)256*256*2);
    float* part = (float*)alloc((size_t)NG*PCH*512*4);
    float* gbuf = (float*)alloc((size_t)NG*2*HID*4);
    float* g1   = (float*)alloc((size_t)NG*HID*4);
    float* g2   = (float*)alloc((size_t)NG*128*4);

    const int* esrc = eidx;
    const int* edst = eidx + NE;
    dim3 blk(256);
    const int NB512 = (NN + 511) / 512;   // 98

    // CSR build
    hipMemsetAsync(cursor, 0, NN*sizeof(int), stream);
    edge_count<<<NE/256, blk, 0, stream>>>(edst, cursor, NE);
    scan_bsums<<<NB512, 512, 0, stream>>>(cursor, bsum, NN);
    scan_top<<<1, 128, 0, stream>>>(bsum, NB512);
    scan_local<<<NB512, 512, 0, stream>>>(cursor, bsum, row_ptr, NN);
    hipMemsetAsync(cursor, 0, NN*sizeof(int), stream);
    edge_fill<<<NE/256, blk, 0, stream>>>(esrc, edst, row_ptr, cursor, col_idx, NE);

    // weight prep (bf16) + combined gi weights: WcombT_s = Wih @ w_s^T, batched over s
    cvt_elem<<<(NSTEPS*HID*HID + 255)/256, blk, 0, stream>>>(ggc_w, wgbf, NSTEPS*HID*HID);
    cvt_elem<<<768, blk, 0, stream>>>(W_ih, WihBf, 768*HID);
    cvt_elem<<<768, blk, 0, stream>>>(W_hh, WhhBf, 768*HID);
    prep_wa1<<<128, blk, 0, stream>>>(Wa1, Wa1t);
    gemm_bf16<<<dim3(2, 6, NSTEPS), blk, 0, stream>>>(
        WihBf, wgbf, nullptr, 0, WcombT, nullptr, 768, HID, HID,
        (size_t)HID*HID, (size_t)768*HID);

    // input projection via split-precision bf16 MFMA:
    //   A' = [bf16(x) | bf16(x - hi)] (K=256), B' = [W_hi | W_hi]
    // Writes hi -> hbfP and lo residual -> hloP. A' aliases hbfQ.
    unsigned short* Ax = hbfQ;
    split_x<<<NN, 128, 0, stream>>>(x, Ax);
    prep_win<<<256, 128, 0, stream>>>(W_in, WinT);
    gemm_bf16<<<dim3(2, (NN+127)/128), blk, 0, stream>>>(
        Ax, WinT, b_in, 1, hbfP, hloP, NN, HID, 256, 0, 0);

    // 5 steps: gather h -> agg_h; gru with combined gi weights (no m-GEMM).
    // Last step fuses the post-loop relu into the gru epilogue.
    unsigned short* hbf  = hbfP;  unsigned short* hlo  = hloP;
    unsigned short* hbfn = hbfQ;  unsigned short* hlon = hloQ;
    const int MB64 = (NN + 63) / 64;   // 782
    for (int s = 0; s < NSTEPS; ++s) {
        gather_agg<<<NN/4, blk, 0, stream>>>(hbf, aggbf, row_ptr, col_idx, NN);
        gru_mfma<<<dim3(HID/64, MB64), blk, 0, stream>>>(
            aggbf, hbf, hlo, hbfn, hlon, WcombT + (size_t)s*768*HID, WhhBf, b_ih, b_hh,
            NN, (s == NSTEPS-1) ? 1 : 0);
        { unsigned short* t0 = hbf; hbf = hbfn; hbfn = t0; }
        { unsigned short* t1 = hlo; hlo = hlon; hlon = t1; }
    }
    // hbf holds bf16 relu(h5); hlo its residual (unused downstream).

    // attention: t = relu(h @ Wa1 + ba1) [bf16, reuses aggbf], a = sigmoid(t @ Wa2 + ba2)
    unsigned short* tbuf = aggbf;
    gemm_bf16<<<dim3(1, (NN+127)/128), blk, 0, stream>>>(hbf, Wa1t, ba1, 1, tbuf, nullptr, NN, 128, HID, 0, 0);
    att_sig<<<NN/4, blk, 0, stream>>>(tbuf, Wa2, ba2, aout, NN);

    // pooling -> g [128, 512] (two-phase, bf16 h mirror)
    pool_partial<<<dim3(NG, PCH), blk, 0, stream>>>(hbf, aout, batch, part, NN);
    pool_final<<<NG, blk, 0, stream>>>(part, batch, gbuf, NN);

    // classifier (fp32, tiny)
    gemm_kn<1><<<dim3(HID/64, (NG+63)/64), blk, 0, stream>>>(gbuf, Wc1, bc1, g1, NG, HID, 2*HID);
    gemm_kn<1><<<dim3(2,      (NG+63)/64), blk, 0, stream>>>(g1,   Wc2, bc2, g2, NG, 128, HID);
    preds_kernel<<<1, blk, 0, stream>>>(g2, Wc3, bc3, out);
}